// Round 5
// baseline (1031.866 us; speedup 1.0000x reference)
//
#include <hip/hip_runtime.h>

#define NN 100000
#define NE 1600000
#define FD 128
#define NC 10
#define NG 64

// ---------- CSR build ----------

__global__ void k_zero_int(int* __restrict__ a, int n) {
  int i = blockIdx.x * 256 + threadIdx.x;
  if (i < n) a[i] = 0;
}

__global__ void k_count(const int* __restrict__ dst, int* __restrict__ cnt) {
  int e = blockIdx.x * 256 + threadIdx.x;
  if (e < NE) atomicAdd(&cnt[dst[e]], 1);
}

// Parallel 3-phase exclusive scan of cnt[NN] -> rowptr; emits dinv and zeroes cnt.
#define NB_SCAN 196       // 196 * 512 = 100352 >= NN
#define SCH 2

__global__ void k_scanA(const int* __restrict__ cnt, int* __restrict__ blockSums) {
  __shared__ int red[256];
  int t = threadIdx.x, b = blockIdx.x;
  int i0 = b * 512 + t * SCH;
  int s = 0;
#pragma unroll
  for (int j = 0; j < SCH; ++j) { int i = i0 + j; if (i < NN) s += cnt[i]; }
  red[t] = s;
  __syncthreads();
  for (int off = 128; off > 0; off >>= 1) {
    if (t < off) red[t] += red[t + off];
    __syncthreads();
  }
  if (t == 0) blockSums[b] = red[0];
}

__global__ void k_scanB(const int* __restrict__ blockSums, int* __restrict__ blockOffs,
                        int* __restrict__ rowptr) {
  __shared__ int sh[256];
  int t = threadIdx.x;
  int v = (t < NB_SCAN) ? blockSums[t] : 0;
  sh[t] = v;
  __syncthreads();
  for (int off = 1; off < 256; off <<= 1) {
    int u = (t >= off) ? sh[t - off] : 0;
    __syncthreads();
    sh[t] += u;
    __syncthreads();
  }
  if (t < NB_SCAN) blockOffs[t] = sh[t] - v;   // exclusive
  if (t == 255) rowptr[NN] = sh[255];
}

__global__ void k_scanC(int* __restrict__ cnt, const int* __restrict__ blockOffs,
                        int* __restrict__ rowptr, float* __restrict__ dinv) {
  __shared__ int sh[256];
  int t = threadIdx.x, b = blockIdx.x;
  int i0 = b * 512 + t * SCH;
  int c[SCH];
  int s = 0;
#pragma unroll
  for (int j = 0; j < SCH; ++j) {
    int i = i0 + j;
    c[j] = (i < NN) ? cnt[i] : 0;
    s += c[j];
  }
  sh[t] = s;
  __syncthreads();
  for (int off = 1; off < 256; off <<= 1) {
    int u = (t >= off) ? sh[t - off] : 0;
    __syncthreads();
    sh[t] += u;
    __syncthreads();
  }
  int run = blockOffs[b] + sh[t] - s;
#pragma unroll
  for (int j = 0; j < SCH; ++j) {
    int i = i0 + j;
    if (i < NN) {
      rowptr[i] = run;
      dinv[i] = rsqrtf((float)c[j] + 1.0f);
      cnt[i] = 0;
      run += c[j];
    }
  }
}

// fill interleaved (src, weight) pairs: one 8-B stream in the gather hot loop
__global__ void k_fill(const int* __restrict__ src, const int* __restrict__ dst,
                       const int* __restrict__ rowptr, int* __restrict__ cursor,
                       const float* __restrict__ dinv, int2* __restrict__ csr_sw) {
  int e = blockIdx.x * 256 + threadIdx.x;
  if (e >= NE) return;
  int d = dst[e], s = src[e];
  int slot = rowptr[d] + atomicAdd(&cursor[d], 1);
  csr_sw[slot] = make_int2(s, __float_as_int(dinv[s] * dinv[d]));
}

// ---------- GEMM: H = X @ W ----------
// No LDS: W reads are wave-uniform per col-group (L1/L2 broadcast), X float4.
// 4x8 register tile per thread, 64 rows per 256-thread block.
__global__ __launch_bounds__(256, 4) void k_gemm(const float* __restrict__ X,
                                                 const float* __restrict__ W,
                                                 float* __restrict__ H) {
  int tid = threadIdx.x;
  int row0 = blockIdx.x * 64 + (tid >> 4) * 4;
  int col0 = (tid & 15) * 8;

  const float* xp[4];
#pragma unroll
  for (int r = 0; r < 4; ++r) {
    int rr = row0 + r;
    if (rr >= NN) rr = NN - 1;           // tail clamp: valid reads, stores masked
    xp[r] = X + (size_t)rr * FD;
  }

  float acc[4][8] = {};
#pragma unroll 2
  for (int kc = 0; kc < FD; kc += 4) {
    float xr[4][4];
#pragma unroll
    for (int r = 0; r < 4; ++r)
      *(float4*)xr[r] = *(const float4*)(xp[r] + kc);
#pragma unroll
    for (int kk = 0; kk < 4; ++kk) {
      float w[8];
      const float* wp = W + (size_t)(kc + kk) * FD + col0;
      *(float4*)&w[0] = *(const float4*)wp;
      *(float4*)&w[4] = *(const float4*)(wp + 4);
#pragma unroll
      for (int r = 0; r < 4; ++r) {
        float xv = xr[r][kk];
#pragma unroll
        for (int c = 0; c < 8; ++c) acc[r][c] = fmaf(xv, w[c], acc[r][c]);
      }
    }
  }

#pragma unroll
  for (int r = 0; r < 4; ++r) {
    int rr = row0 + r;
    if (rr < NN) {
      float* hp = H + (size_t)rr * FD + col0;
      *(float4*)hp = *(float4*)&acc[r][0];
      *(float4*)(hp + 4) = *(float4*)&acc[r][4];
    }
  }
}

// ---------- gather: OUT[i] = relu(dinv_i^2*H[i] + b + sum_e w_e * H[src_e]) ----------
// 32 lanes per node (float4/lane); 4 edge-rows in flight per iteration.
__global__ void k_gather(const int* __restrict__ rowptr, const int2* __restrict__ csr_sw,
                         const float* __restrict__ dinv, const float* __restrict__ H,
                         const float* __restrict__ b, float* __restrict__ OUT) {
  int node = blockIdx.x * 8 + (threadIdx.x >> 5);
  if (node >= NN) return;
  int lane = threadIdx.x & 31;
  const float4* __restrict__ H4 = (const float4*)H;
  float di = dinv[node];
  float4 hv = H4[(size_t)node * 32 + lane];
  float4 bv = ((const float4*)b)[lane];
  float4 acc;
  float dii = di * di;
  acc.x = fmaf(dii, hv.x, bv.x);
  acc.y = fmaf(dii, hv.y, bv.y);
  acc.z = fmaf(dii, hv.z, bv.z);
  acc.w = fmaf(dii, hv.w, bv.w);
  int e0 = rowptr[node], e1 = rowptr[node + 1];
  int e = e0;
  for (; e + 3 < e1; e += 4) {
    int2 p0 = csr_sw[e], p1 = csr_sw[e + 1], p2 = csr_sw[e + 2], p3 = csr_sw[e + 3];
    float4 v0 = H4[(size_t)p0.x * 32 + lane];
    float4 v1 = H4[(size_t)p1.x * 32 + lane];
    float4 v2 = H4[(size_t)p2.x * 32 + lane];
    float4 v3 = H4[(size_t)p3.x * 32 + lane];
    float w0 = __int_as_float(p0.y), w1 = __int_as_float(p1.y);
    float w2 = __int_as_float(p2.y), w3 = __int_as_float(p3.y);
    acc.x = fmaf(w0, v0.x, acc.x); acc.y = fmaf(w0, v0.y, acc.y);
    acc.z = fmaf(w0, v0.z, acc.z); acc.w = fmaf(w0, v0.w, acc.w);
    acc.x = fmaf(w1, v1.x, acc.x); acc.y = fmaf(w1, v1.y, acc.y);
    acc.z = fmaf(w1, v1.z, acc.z); acc.w = fmaf(w1, v1.w, acc.w);
    acc.x = fmaf(w2, v2.x, acc.x); acc.y = fmaf(w2, v2.y, acc.y);
    acc.z = fmaf(w2, v2.z, acc.z); acc.w = fmaf(w2, v2.w, acc.w);
    acc.x = fmaf(w3, v3.x, acc.x); acc.y = fmaf(w3, v3.y, acc.y);
    acc.z = fmaf(w3, v3.z, acc.z); acc.w = fmaf(w3, v3.w, acc.w);
  }
  for (; e < e1; ++e) {
    int2 p0 = csr_sw[e];
    float w0 = __int_as_float(p0.y);
    float4 v0 = H4[(size_t)p0.x * 32 + lane];
    acc.x = fmaf(w0, v0.x, acc.x); acc.y = fmaf(w0, v0.y, acc.y);
    acc.z = fmaf(w0, v0.z, acc.z); acc.w = fmaf(w0, v0.w, acc.w);
  }
  acc.x = fmaxf(acc.x, 0.f); acc.y = fmaxf(acc.y, 0.f);
  acc.z = fmaxf(acc.z, 0.f); acc.w = fmaxf(acc.w, 0.f);
  ((float4*)OUT)[(size_t)node * 32 + lane] = acc;
}

// ---------- pooling + head ----------

__global__ void k_zero_pool(float* __restrict__ sums, float* __restrict__ counts) {
  int t = blockIdx.x * 256 + threadIdx.x;
  if (t < NG * FD) sums[t] = 0.f;
  if (t < NG) counts[t] = 0.f;
}

#define POOL_BLOCKS 1024
#define POOL_CHUNK 98
__global__ void k_pool(const int* __restrict__ batch, const float* __restrict__ H,
                       float* __restrict__ sums, float* __restrict__ counts) {
  int f = threadIdx.x;  // 0..127
  int i0 = blockIdx.x * POOL_CHUNK;
  if (i0 >= NN) return;
  int i1 = i0 + POOL_CHUNK;
  if (i1 > NN) i1 = NN;
  float acc = 0.f;
  int gcur = batch[i0];
  int cnt = 0;
  for (int i = i0; i < i1; ++i) {
    int g = batch[i];
    if (g != gcur) {
      atomicAdd(&sums[gcur * FD + f], acc);
      if (f == 0) atomicAdd(&counts[gcur], (float)cnt);
      acc = 0.f; cnt = 0; gcur = g;
    }
    acc += H[(size_t)i * FD + f];
    ++cnt;
  }
  atomicAdd(&sums[gcur * FD + f], acc);
  if (f == 0) atomicAdd(&counts[gcur], (float)cnt);
}

__global__ void k_head(const float* __restrict__ sums, const float* __restrict__ counts,
                       const float* __restrict__ Wm, const float* __restrict__ bm,
                       float* __restrict__ out) {
  int t = blockIdx.x * 256 + threadIdx.x;
  if (t >= NG * NC) return;
  int g = t / NC, c = t % NC;
  float inv = 1.0f / fmaxf(counts[g], 1.0f);
  float s = 0.f;
#pragma unroll 4
  for (int f = 0; f < FD; ++f) s = fmaf(sums[g * FD + f] * inv, Wm[f * NC + c], s);
  out[t] = s + bm[c];
}

extern "C" void kernel_launch(void* const* d_in, const int* in_sizes, int n_in,
                              void* d_out, int out_size, void* d_ws, size_t ws_size,
                              hipStream_t stream) {
  const float* x     = (const float*)d_in[0];
  const int*   ei    = (const int*)d_in[1];
  const int*   batch = (const int*)d_in[2];
  const float* W_in  = (const float*)d_in[3];
  const float* b_in  = (const float*)d_in[4];
  const float* W_mid = (const float*)d_in[5];
  const float* b_mid = (const float*)d_in[6];
  const float* W_mlp = (const float*)d_in[7];
  const float* b_mlp = (const float*)d_in[8];
  float* out = (float*)d_out;

  const int* src = ei;        // edge_index[0]
  const int* dst = ei + NE;   // edge_index[1]

  char* ws = (char*)d_ws;
  float* P         = (float*)ws;  ws += (size_t)NN * FD * 4;   // 51.2 MB
  float* Q         = (float*)ws;  ws += (size_t)NN * FD * 4;   // 51.2 MB
  float* dinv      = (float*)ws;  ws += (size_t)NN * 4;
  int*   rowptr    = (int*)ws;    ws += (size_t)(NN + 1) * 4;
  int*   cursor    = (int*)ws;    ws += (size_t)NN * 4;
  int2*  csr_sw    = (int2*)ws;   ws += (size_t)NE * 8;        // 12.8 MB
  int*   blockSums = (int*)ws;    ws += 256 * 4;
  int*   blockOffs = (int*)ws;    ws += 256 * 4;
  float* sums      = (float*)ws;  ws += (size_t)NG * FD * 4;
  float* counts    = (float*)ws;  ws += (size_t)NG * 4;

  // CSR build (reused by all 4 layers)
  k_zero_int<<<(NN + 255) / 256, 256, 0, stream>>>(cursor, NN);
  k_count<<<(NE + 255) / 256, 256, 0, stream>>>(dst, cursor);
  k_scanA<<<NB_SCAN, 256, 0, stream>>>(cursor, blockSums);
  k_scanB<<<1, 256, 0, stream>>>(blockSums, blockOffs, rowptr);
  k_scanC<<<NB_SCAN, 256, 0, stream>>>(cursor, blockOffs, rowptr, dinv);
  k_fill<<<(NE + 255) / 256, 256, 0, stream>>>(src, dst, rowptr, cursor, dinv, csr_sw);

  const int gM = (NN + 63) / 64;   // 1563 blocks
  const int gG = (NN + 7) / 8;     // 12500 blocks
  for (int L = 0; L < 4; ++L) {
    const float* X = (L == 0) ? x : P;
    const float* W = (L == 0) ? W_in : W_mid;
    const float* b = (L == 0) ? b_in : b_mid;
    k_gemm<<<gM, 256, 0, stream>>>(X, W, Q);
    k_gather<<<gG, 256, 0, stream>>>(rowptr, csr_sw, dinv, Q, b, P);
  }

  k_zero_pool<<<32, 256, 0, stream>>>(sums, counts);
  k_pool<<<POOL_BLOCKS, 128, 0, stream>>>(batch, P, sums, counts);
  k_head<<<(NG * NC + 255) / 256, 256, 0, stream>>>(sums, counts, W_mlp, b_mlp, out);
}

// Round 6
// 858.677 us; speedup vs baseline: 1.2017x; 1.2017x over previous
//
#include <hip/hip_runtime.h>

#define NN 100000
#define NE 1600000
#define FD 128
#define NC 10
#define NG 64

typedef __attribute__((ext_vector_type(8))) short short8v;   // 8 bf16 (4 VGPRs)
typedef __attribute__((ext_vector_type(4))) float f32x4;

__device__ inline ushort f2bf(float x) {                     // round-to-nearest-even
  unsigned u = __float_as_uint(x);
  return (ushort)((u + 0x7FFF + ((u >> 16) & 1)) >> 16);
}
__device__ inline float bf2f(ushort h) { return __uint_as_float(((unsigned)h) << 16); }

// ---------- CSR build ----------

__global__ void k_zero_int(int* __restrict__ a, int n) {
  int i = blockIdx.x * 256 + threadIdx.x;
  if (i < n) a[i] = 0;
}

__global__ void k_count(const int* __restrict__ dst, int* __restrict__ cnt) {
  int e = blockIdx.x * 256 + threadIdx.x;
  if (e < NE) atomicAdd(&cnt[dst[e]], 1);
}

#define NB_SCAN 196       // 196 * 512 = 100352 >= NN
#define SCH 2

__global__ void k_scanA(const int* __restrict__ cnt, int* __restrict__ blockSums) {
  __shared__ int red[256];
  int t = threadIdx.x, b = blockIdx.x;
  int i0 = b * 512 + t * SCH;
  int s = 0;
#pragma unroll
  for (int j = 0; j < SCH; ++j) { int i = i0 + j; if (i < NN) s += cnt[i]; }
  red[t] = s;
  __syncthreads();
  for (int off = 128; off > 0; off >>= 1) {
    if (t < off) red[t] += red[t + off];
    __syncthreads();
  }
  if (t == 0) blockSums[b] = red[0];
}

__global__ void k_scanB(const int* __restrict__ blockSums, int* __restrict__ blockOffs,
                        int* __restrict__ rowptr) {
  __shared__ int sh[256];
  int t = threadIdx.x;
  int v = (t < NB_SCAN) ? blockSums[t] : 0;
  sh[t] = v;
  __syncthreads();
  for (int off = 1; off < 256; off <<= 1) {
    int u = (t >= off) ? sh[t - off] : 0;
    __syncthreads();
    sh[t] += u;
    __syncthreads();
  }
  if (t < NB_SCAN) blockOffs[t] = sh[t] - v;
  if (t == 255) rowptr[NN] = sh[255];
}

__global__ void k_scanC(int* __restrict__ cnt, const int* __restrict__ blockOffs,
                        int* __restrict__ rowptr, float* __restrict__ dinv) {
  __shared__ int sh[256];
  int t = threadIdx.x, b = blockIdx.x;
  int i0 = b * 512 + t * SCH;
  int c[SCH];
  int s = 0;
#pragma unroll
  for (int j = 0; j < SCH; ++j) {
    int i = i0 + j;
    c[j] = (i < NN) ? cnt[i] : 0;
    s += c[j];
  }
  sh[t] = s;
  __syncthreads();
  for (int off = 1; off < 256; off <<= 1) {
    int u = (t >= off) ? sh[t - off] : 0;
    __syncthreads();
    sh[t] += u;
    __syncthreads();
  }
  int run = blockOffs[b] + sh[t] - s;
#pragma unroll
  for (int j = 0; j < SCH; ++j) {
    int i = i0 + j;
    if (i < NN) {
      rowptr[i] = run;
      dinv[i] = rsqrtf((float)c[j] + 1.0f);
      cnt[i] = 0;
      run += c[j];
    }
  }
}

__global__ void k_fill(const int* __restrict__ src, const int* __restrict__ dst,
                       const int* __restrict__ rowptr, int* __restrict__ cursor,
                       const float* __restrict__ dinv, int2* __restrict__ csr_sw) {
  int e = blockIdx.x * 256 + threadIdx.x;
  if (e >= NE) return;
  int d = dst[e], s = src[e];
  int slot = rowptr[d] + atomicAdd(&cursor[d], 1);
  csr_sw[slot] = make_int2(s, __float_as_int(dinv[s] * dinv[d]));
}

// ---------- split-bf16 prep ----------

// f32 -> (hi, lo) bf16 pair, 4 elems/thread
__global__ void k_split(const float* __restrict__ X, ushort* __restrict__ Hh,
                        ushort* __restrict__ Hl) {
  int t = blockIdx.x * 256 + threadIdx.x;
  if (t >= NN * FD / 4) return;
  float4 v = ((const float4*)X)[t];
  ushort4 h, l;
  h.x = f2bf(v.x); l.x = f2bf(v.x - bf2f(h.x));
  h.y = f2bf(v.y); l.y = f2bf(v.y - bf2f(h.y));
  h.z = f2bf(v.z); l.z = f2bf(v.z - bf2f(h.z));
  h.w = f2bf(v.w); l.w = f2bf(v.w - bf2f(h.w));
  ((ushort4*)Hh)[t] = h;
  ((ushort4*)Hl)[t] = l;
}

// Pack W[k][col] (row-major f32) into MFMA B-fragment order, split hi/lo:
// packed[(((k>>5)*128 + col)*4 + ((k>>3)&3))*8 + (k&7)]
__global__ void k_packW(const float* __restrict__ W, ushort* __restrict__ Wh,
                        ushort* __restrict__ Wl) {
  int idx = blockIdx.x * 256 + threadIdx.x;
  if (idx >= FD * FD) return;
  int k = idx >> 7, col = idx & 127;
  float v = W[idx];
  ushort h = f2bf(v);
  ushort l = f2bf(v - bf2f(h));
  size_t o = ((((size_t)(k >> 5)) * 128 + col) * 4 + ((k >> 3) & 3)) * 8 + (k & 7);
  Wh[o] = h; Wl[o] = l;
}

// ---------- MFMA GEMM: Q = (Ah+Al) @ (Wh+Wl), dropping Al@Wl ----------
// 4 waves/block, 16 rows/wave, 64 rows/block. K=128 fully unrolled.
// A-frag: lane = m + 16*k0, 8 contiguous k elems.  B pre-packed (k_packW).
__global__ __launch_bounds__(256, 4) void k_gemm_mfma(
    const ushort* __restrict__ Ah, const ushort* __restrict__ Al,
    const ushort* __restrict__ Bh, const ushort* __restrict__ Bl,
    float* __restrict__ Q) {
  int tid = threadIdx.x;
  int wave = tid >> 6, lane = tid & 63;
  int m15 = lane & 15, k0 = lane >> 4;          // k0 in 0..3
  int row0 = blockIdx.x * 64 + wave * 16;

  int ar = row0 + m15; if (ar >= NN) ar = NN - 1;   // clamp reads; stores masked
  short8v ah[4], al[4];
#pragma unroll
  for (int kc = 0; kc < 4; ++kc) {
    const ushort* p = Ah + (size_t)ar * FD + kc * 32 + k0 * 8;
    const ushort* q = Al + (size_t)ar * FD + kc * 32 + k0 * 8;
    ah[kc] = *(const short8v*)p;
    al[kc] = *(const short8v*)q;
  }

  int orow = row0 + k0 * 4;
#pragma unroll
  for (int nt = 0; nt < 8; ++nt) {
    int col = nt * 16 + m15;
    f32x4 acc = {0.f, 0.f, 0.f, 0.f};
#pragma unroll
    for (int kc = 0; kc < 4; ++kc) {
      size_t off = (((size_t)kc * 128 + col) * 4 + k0) * 8;
      short8v bh = *(const short8v*)(Bh + off);
      short8v bl = *(const short8v*)(Bl + off);
      acc = __builtin_amdgcn_mfma_f32_16x16x32_bf16(ah[kc], bh, acc, 0, 0, 0);
      acc = __builtin_amdgcn_mfma_f32_16x16x32_bf16(ah[kc], bl, acc, 0, 0, 0);
      acc = __builtin_amdgcn_mfma_f32_16x16x32_bf16(al[kc], bh, acc, 0, 0, 0);
    }
#pragma unroll
    for (int j = 0; j < 4; ++j) {
      int r = orow + j;
      if (r < NN) Q[(size_t)r * FD + col] = acc[j];
    }
  }
}

// ---------- gather: relu(dinv^2*H + b + sum w*H[src]) -> bf16 hi/lo ----------
__global__ void k_gather(const int* __restrict__ rowptr, const int2* __restrict__ csr_sw,
                         const float* __restrict__ dinv, const float* __restrict__ H,
                         const float* __restrict__ b,
                         ushort* __restrict__ Ph, ushort* __restrict__ Pl) {
  int node = blockIdx.x * 8 + (threadIdx.x >> 5);
  if (node >= NN) return;
  int lane = threadIdx.x & 31;
  const float4* __restrict__ H4 = (const float4*)H;
  float di = dinv[node];
  float4 hv = H4[(size_t)node * 32 + lane];
  float4 bv = ((const float4*)b)[lane];
  float4 acc;
  float dii = di * di;
  acc.x = fmaf(dii, hv.x, bv.x);
  acc.y = fmaf(dii, hv.y, bv.y);
  acc.z = fmaf(dii, hv.z, bv.z);
  acc.w = fmaf(dii, hv.w, bv.w);
  int e0 = rowptr[node], e1 = rowptr[node + 1];
  int e = e0;
  for (; e + 3 < e1; e += 4) {
    int2 p0 = csr_sw[e], p1 = csr_sw[e + 1], p2 = csr_sw[e + 2], p3 = csr_sw[e + 3];
    float4 v0 = H4[(size_t)p0.x * 32 + lane];
    float4 v1 = H4[(size_t)p1.x * 32 + lane];
    float4 v2 = H4[(size_t)p2.x * 32 + lane];
    float4 v3 = H4[(size_t)p3.x * 32 + lane];
    float w0 = __int_as_float(p0.y), w1 = __int_as_float(p1.y);
    float w2 = __int_as_float(p2.y), w3 = __int_as_float(p3.y);
    acc.x = fmaf(w0, v0.x, acc.x); acc.y = fmaf(w0, v0.y, acc.y);
    acc.z = fmaf(w0, v0.z, acc.z); acc.w = fmaf(w0, v0.w, acc.w);
    acc.x = fmaf(w1, v1.x, acc.x); acc.y = fmaf(w1, v1.y, acc.y);
    acc.z = fmaf(w1, v1.z, acc.z); acc.w = fmaf(w1, v1.w, acc.w);
    acc.x = fmaf(w2, v2.x, acc.x); acc.y = fmaf(w2, v2.y, acc.y);
    acc.z = fmaf(w2, v2.z, acc.z); acc.w = fmaf(w2, v2.w, acc.w);
    acc.x = fmaf(w3, v3.x, acc.x); acc.y = fmaf(w3, v3.y, acc.y);
    acc.z = fmaf(w3, v3.z, acc.z); acc.w = fmaf(w3, v3.w, acc.w);
  }
  for (; e < e1; ++e) {
    int2 p0 = csr_sw[e];
    float w0 = __int_as_float(p0.y);
    float4 v0 = H4[(size_t)p0.x * 32 + lane];
    acc.x = fmaf(w0, v0.x, acc.x); acc.y = fmaf(w0, v0.y, acc.y);
    acc.z = fmaf(w0, v0.z, acc.z); acc.w = fmaf(w0, v0.w, acc.w);
  }
  acc.x = fmaxf(acc.x, 0.f); acc.y = fmaxf(acc.y, 0.f);
  acc.z = fmaxf(acc.z, 0.f); acc.w = fmaxf(acc.w, 0.f);
  ushort4 h, l;
  h.x = f2bf(acc.x); l.x = f2bf(acc.x - bf2f(h.x));
  h.y = f2bf(acc.y); l.y = f2bf(acc.y - bf2f(h.y));
  h.z = f2bf(acc.z); l.z = f2bf(acc.z - bf2f(h.z));
  h.w = f2bf(acc.w); l.w = f2bf(acc.w - bf2f(h.w));
  size_t o = (size_t)node * 32 + lane;     // ushort4 index
  ((ushort4*)Ph)[o] = h;
  ((ushort4*)Pl)[o] = l;
}

// ---------- pooling + head ----------

__global__ void k_zero_pool(float* __restrict__ sums, float* __restrict__ counts) {
  int t = blockIdx.x * 256 + threadIdx.x;
  if (t < NG * FD) sums[t] = 0.f;
  if (t < NG) counts[t] = 0.f;
}

#define POOL_BLOCKS 1024
#define POOL_CHUNK 98
__global__ void k_pool(const int* __restrict__ batch, const ushort* __restrict__ Ph,
                       const ushort* __restrict__ Pl, float* __restrict__ sums,
                       float* __restrict__ counts) {
  int f = threadIdx.x;  // 0..127
  int i0 = blockIdx.x * POOL_CHUNK;
  if (i0 >= NN) return;
  int i1 = i0 + POOL_CHUNK;
  if (i1 > NN) i1 = NN;
  float acc = 0.f;
  int gcur = batch[i0];
  int cnt = 0;
  for (int i = i0; i < i1; ++i) {
    int g = batch[i];
    if (g != gcur) {
      atomicAdd(&sums[gcur * FD + f], acc);
      if (f == 0) atomicAdd(&counts[gcur], (float)cnt);
      acc = 0.f; cnt = 0; gcur = g;
    }
    size_t o = (size_t)i * FD + f;
    acc += bf2f(Ph[o]) + bf2f(Pl[o]);
    ++cnt;
  }
  atomicAdd(&sums[gcur * FD + f], acc);
  if (f == 0) atomicAdd(&counts[gcur], (float)cnt);
}

__global__ void k_head(const float* __restrict__ sums, const float* __restrict__ counts,
                       const float* __restrict__ Wm, const float* __restrict__ bm,
                       float* __restrict__ out) {
  int t = blockIdx.x * 256 + threadIdx.x;
  if (t >= NG * NC) return;
  int g = t / NC, c = t % NC;
  float inv = 1.0f / fmaxf(counts[g], 1.0f);
  float s = 0.f;
#pragma unroll 4
  for (int f = 0; f < FD; ++f) s = fmaf(sums[g * FD + f] * inv, Wm[f * NC + c], s);
  out[t] = s + bm[c];
}

extern "C" void kernel_launch(void* const* d_in, const int* in_sizes, int n_in,
                              void* d_out, int out_size, void* d_ws, size_t ws_size,
                              hipStream_t stream) {
  const float* x     = (const float*)d_in[0];
  const int*   ei    = (const int*)d_in[1];
  const int*   batch = (const int*)d_in[2];
  const float* W_in  = (const float*)d_in[3];
  const float* b_in  = (const float*)d_in[4];
  const float* W_mid = (const float*)d_in[5];
  const float* b_mid = (const float*)d_in[6];
  const float* W_mlp = (const float*)d_in[7];
  const float* b_mlp = (const float*)d_in[8];
  float* out = (float*)d_out;

  const int* src = ei;        // edge_index[0]
  const int* dst = ei + NE;   // edge_index[1]

  char* ws = (char*)d_ws;
  float*  Q         = (float*)ws;   ws += (size_t)NN * FD * 4;   // 51.2 MB
  ushort* Ph        = (ushort*)ws;  ws += (size_t)NN * FD * 2;   // 25.6 MB
  ushort* Pl        = (ushort*)ws;  ws += (size_t)NN * FD * 2;   // 25.6 MB
  float*  dinv      = (float*)ws;   ws += (size_t)NN * 4;
  int*    rowptr    = (int*)ws;     ws += (size_t)(NN + 1) * 4;
  int*    cursor    = (int*)ws;     ws += (size_t)NN * 4;
  int2*   csr_sw    = (int2*)ws;    ws += (size_t)NE * 8;        // 12.8 MB
  int*    blockSums = (int*)ws;     ws += 256 * 4;
  int*    blockOffs = (int*)ws;     ws += 256 * 4;
  ushort* WhA       = (ushort*)ws;  ws += (size_t)FD * FD * 2;   // packed W_in hi
  ushort* WlA       = (ushort*)ws;  ws += (size_t)FD * FD * 2;
  ushort* WhB       = (ushort*)ws;  ws += (size_t)FD * FD * 2;   // packed W_mid hi
  ushort* WlB       = (ushort*)ws;  ws += (size_t)FD * FD * 2;
  float*  sums      = (float*)ws;   ws += (size_t)NG * FD * 4;
  float*  counts    = (float*)ws;   ws += (size_t)NG * 4;

  // CSR build (reused by all 4 layers)
  k_zero_int<<<(NN + 255) / 256, 256, 0, stream>>>(cursor, NN);
  k_count<<<(NE + 255) / 256, 256, 0, stream>>>(dst, cursor);
  k_scanA<<<NB_SCAN, 256, 0, stream>>>(cursor, blockSums);
  k_scanB<<<1, 256, 0, stream>>>(blockSums, blockOffs, rowptr);
  k_scanC<<<NB_SCAN, 256, 0, stream>>>(cursor, blockOffs, rowptr, dinv);
  k_fill<<<(NE + 255) / 256, 256, 0, stream>>>(src, dst, rowptr, cursor, dinv, csr_sw);

  // weight packing + input split
  k_packW<<<(FD * FD + 255) / 256, 256, 0, stream>>>(W_in, WhA, WlA);
  k_packW<<<(FD * FD + 255) / 256, 256, 0, stream>>>(W_mid, WhB, WlB);
  k_split<<<(NN * FD / 4 + 255) / 256, 256, 0, stream>>>(x, Ph, Pl);

  const int gM = (NN + 63) / 64;   // 1563 blocks
  const int gG = (NN + 7) / 8;     // 12500 blocks
  for (int L = 0; L < 4; ++L) {
    const ushort* Wh = (L == 0) ? WhA : WhB;
    const ushort* Wl = (L == 0) ? WlA : WlB;
    const float*  b  = (L == 0) ? b_in : b_mid;
    k_gemm_mfma<<<gM, 256, 0, stream>>>(Ph, Pl, Wh, Wl, Q);
    k_gather<<<gG, 256, 0, stream>>>(rowptr, csr_sw, dinv, Q, b, Ph, Pl);
  }

  k_zero_pool<<<32, 256, 0, stream>>>(sums, counts);
  k_pool<<<POOL_BLOCKS, 128, 0, stream>>>(batch, Ph, Pl, sums, counts);
  k_head<<<(NG * NC + 255) / 256, 256, 0, stream>>>(sums, counts, W_mlp, b_mlp, out);
}

// Round 7
// 637.556 us; speedup vs baseline: 1.6185x; 1.3468x over previous
//
#include <hip/hip_runtime.h>

#define NN 100000
#define NE 1600000
#define NT (NE + NN)     // edges incl. self-loops
#define FD 128
#define NC 10
#define NG 64

typedef __attribute__((ext_vector_type(8))) short short8v;   // 8 bf16 (4 VGPRs)
typedef __attribute__((ext_vector_type(4))) float f32x4;

__device__ inline ushort f2bf(float x) {                     // round-to-nearest-even
  unsigned u = __float_as_uint(x);
  return (ushort)((u + 0x7FFF + ((u >> 16) & 1)) >> 16);
}
__device__ inline float bf2f(ushort h) { return __uint_as_float(((unsigned)h) << 16); }

// ---------- CSR build (self-loops included as explicit edges) ----------

__global__ void k_one_int(int* __restrict__ a, int n) {
  int i = blockIdx.x * 256 + threadIdx.x;
  if (i < n) a[i] = 1;                     // self-loop pre-counted
}

__global__ void k_count(const int* __restrict__ dst, int* __restrict__ cnt) {
  int e = blockIdx.x * 256 + threadIdx.x;
  if (e < NE) atomicAdd(&cnt[dst[e]], 1);
}

#define NB_SCAN 196       // 196 * 512 = 100352 >= NN
#define SCH 2

__global__ void k_scanA(const int* __restrict__ cnt, int* __restrict__ blockSums) {
  __shared__ int red[256];
  int t = threadIdx.x, b = blockIdx.x;
  int i0 = b * 512 + t * SCH;
  int s = 0;
#pragma unroll
  for (int j = 0; j < SCH; ++j) { int i = i0 + j; if (i < NN) s += cnt[i]; }
  red[t] = s;
  __syncthreads();
  for (int off = 128; off > 0; off >>= 1) {
    if (t < off) red[t] += red[t + off];
    __syncthreads();
  }
  if (t == 0) blockSums[b] = red[0];
}

__global__ void k_scanB(const int* __restrict__ blockSums, int* __restrict__ blockOffs,
                        int* __restrict__ rowptr) {
  __shared__ int sh[256];
  int t = threadIdx.x;
  int v = (t < NB_SCAN) ? blockSums[t] : 0;
  sh[t] = v;
  __syncthreads();
  for (int off = 1; off < 256; off <<= 1) {
    int u = (t >= off) ? sh[t - off] : 0;
    __syncthreads();
    sh[t] += u;
    __syncthreads();
  }
  if (t < NB_SCAN) blockOffs[t] = sh[t] - v;
  if (t == 255) rowptr[NN] = sh[255];      // = NT
}

__global__ void k_scanC(int* __restrict__ cnt, const int* __restrict__ blockOffs,
                        int* __restrict__ rowptr, float* __restrict__ dinv) {
  __shared__ int sh[256];
  int t = threadIdx.x, b = blockIdx.x;
  int i0 = b * 512 + t * SCH;
  int c[SCH];
  int s = 0;
#pragma unroll
  for (int j = 0; j < SCH; ++j) {
    int i = i0 + j;
    c[j] = (i < NN) ? cnt[i] : 0;
    s += c[j];
  }
  sh[t] = s;
  __syncthreads();
  for (int off = 1; off < 256; off <<= 1) {
    int u = (t >= off) ? sh[t - off] : 0;
    __syncthreads();
    sh[t] += u;
    __syncthreads();
  }
  int run = blockOffs[b] + sh[t] - s;
#pragma unroll
  for (int j = 0; j < SCH; ++j) {
    int i = i0 + j;
    if (i < NN) {
      rowptr[i] = run;
      dinv[i] = rsqrtf((float)c[j]);       // c already = deg + 1
      cnt[i] = 0;                          // becomes the fill cursor
      run += c[j];
    }
  }
}

// fills real edges (w = dinv_s*dinv_d) and self-loops (w = dinv_i^2)
__global__ void k_fill(const int* __restrict__ src, const int* __restrict__ dst,
                       const int* __restrict__ rowptr, int* __restrict__ cursor,
                       const float* __restrict__ dinv, int2* __restrict__ csr_sw) {
  int e = blockIdx.x * 256 + threadIdx.x;
  if (e >= NT) return;
  int d, s; float w;
  if (e < NE) {
    d = dst[e]; s = src[e];
    w = dinv[s] * dinv[d];
  } else {
    d = e - NE; s = d;
    float di = dinv[d];
    w = di * di;
  }
  int slot = rowptr[d] + atomicAdd(&cursor[d], 1);
  csr_sw[slot] = make_int2(s, __float_as_int(w));
}

// ---------- split-bf16 prep ----------

__global__ void k_split(const float* __restrict__ X, ushort* __restrict__ Hh,
                        ushort* __restrict__ Hl) {
  int t = blockIdx.x * 256 + threadIdx.x;
  if (t >= NN * FD / 4) return;
  float4 v = ((const float4*)X)[t];
  ushort4 h, l;
  h.x = f2bf(v.x); l.x = f2bf(v.x - bf2f(h.x));
  h.y = f2bf(v.y); l.y = f2bf(v.y - bf2f(h.y));
  h.z = f2bf(v.z); l.z = f2bf(v.z - bf2f(h.z));
  h.w = f2bf(v.w); l.w = f2bf(v.w - bf2f(h.w));
  ((ushort4*)Hh)[t] = h;
  ((ushort4*)Hl)[t] = l;
}

// Pack W[k][col] into MFMA B-fragment order, split hi/lo:
// packed[(((k>>5)*128 + col)*4 + ((k>>3)&3))*8 + (k&7)]
__global__ void k_packW(const float* __restrict__ W, ushort* __restrict__ Wh,
                        ushort* __restrict__ Wl) {
  int idx = blockIdx.x * 256 + threadIdx.x;
  if (idx >= FD * FD) return;
  int k = idx >> 7, col = idx & 127;
  float v = W[idx];
  ushort h = f2bf(v);
  ushort l = f2bf(v - bf2f(h));
  size_t o = ((((size_t)(k >> 5)) * 128 + col) * 4 + ((k >> 3) & 3)) * 8 + (k & 7);
  Wh[o] = h; Wl[o] = l;
}

// ---------- MFMA GEMM: Qh = bf16( (Ah+Al) @ (Wh+Wl) ), dropping Al@Wl ----------
__global__ __launch_bounds__(256, 4) void k_gemm_mfma(
    const ushort* __restrict__ Ah, const ushort* __restrict__ Al,
    const ushort* __restrict__ Bh, const ushort* __restrict__ Bl,
    ushort* __restrict__ Qh) {
  int tid = threadIdx.x;
  int wave = tid >> 6, lane = tid & 63;
  int m15 = lane & 15, k0 = lane >> 4;
  int row0 = blockIdx.x * 64 + wave * 16;

  int ar = row0 + m15; if (ar >= NN) ar = NN - 1;
  short8v ah[4], al[4];
#pragma unroll
  for (int kc = 0; kc < 4; ++kc) {
    const ushort* p = Ah + (size_t)ar * FD + kc * 32 + k0 * 8;
    const ushort* q = Al + (size_t)ar * FD + kc * 32 + k0 * 8;
    ah[kc] = *(const short8v*)p;
    al[kc] = *(const short8v*)q;
  }

  int orow = row0 + k0 * 4;
#pragma unroll
  for (int nt = 0; nt < 8; ++nt) {
    int col = nt * 16 + m15;
    f32x4 acc = {0.f, 0.f, 0.f, 0.f};
#pragma unroll
    for (int kc = 0; kc < 4; ++kc) {
      size_t off = (((size_t)kc * 128 + col) * 4 + k0) * 8;
      short8v bh = *(const short8v*)(Bh + off);
      short8v bl = *(const short8v*)(Bl + off);
      acc = __builtin_amdgcn_mfma_f32_16x16x32_bf16(ah[kc], bh, acc, 0, 0, 0);
      acc = __builtin_amdgcn_mfma_f32_16x16x32_bf16(ah[kc], bl, acc, 0, 0, 0);
      acc = __builtin_amdgcn_mfma_f32_16x16x32_bf16(al[kc], bh, acc, 0, 0, 0);
    }
#pragma unroll
    for (int j = 0; j < 4; ++j) {
      int r = orow + j;
      if (r < NN) Qh[(size_t)r * FD + col] = f2bf(acc[j]);
    }
  }
}

// ---------- gather: Ph,Pl = split( relu( b + sum_e w_e * Qh[src_e] ) ) ----------
// self-loop is one of the CSR edges. 32 lanes/node, ushort4 (4 bf16) per lane.
__global__ void k_gather(const int* __restrict__ rowptr, const int2* __restrict__ csr_sw,
                         const ushort* __restrict__ Qh, const float* __restrict__ b,
                         ushort* __restrict__ Ph, ushort* __restrict__ Pl) {
  int node = blockIdx.x * 8 + (threadIdx.x >> 5);
  if (node >= NN) return;
  int lane = threadIdx.x & 31;
  const ushort4* __restrict__ Q4 = (const ushort4*)Qh;
  float4 acc = ((const float4*)b)[lane];
  int e0 = rowptr[node], e1 = rowptr[node + 1];
  int e = e0;
  for (; e + 3 < e1; e += 4) {
    int2 p0 = csr_sw[e], p1 = csr_sw[e + 1], p2 = csr_sw[e + 2], p3 = csr_sw[e + 3];
    ushort4 q0 = Q4[(size_t)p0.x * 32 + lane];
    ushort4 q1 = Q4[(size_t)p1.x * 32 + lane];
    ushort4 q2 = Q4[(size_t)p2.x * 32 + lane];
    ushort4 q3 = Q4[(size_t)p3.x * 32 + lane];
    float w0 = __int_as_float(p0.y), w1 = __int_as_float(p1.y);
    float w2 = __int_as_float(p2.y), w3 = __int_as_float(p3.y);
    acc.x = fmaf(w0, bf2f(q0.x), acc.x); acc.y = fmaf(w0, bf2f(q0.y), acc.y);
    acc.z = fmaf(w0, bf2f(q0.z), acc.z); acc.w = fmaf(w0, bf2f(q0.w), acc.w);
    acc.x = fmaf(w1, bf2f(q1.x), acc.x); acc.y = fmaf(w1, bf2f(q1.y), acc.y);
    acc.z = fmaf(w1, bf2f(q1.z), acc.z); acc.w = fmaf(w1, bf2f(q1.w), acc.w);
    acc.x = fmaf(w2, bf2f(q2.x), acc.x); acc.y = fmaf(w2, bf2f(q2.y), acc.y);
    acc.z = fmaf(w2, bf2f(q2.z), acc.z); acc.w = fmaf(w2, bf2f(q2.w), acc.w);
    acc.x = fmaf(w3, bf2f(q3.x), acc.x); acc.y = fmaf(w3, bf2f(q3.y), acc.y);
    acc.z = fmaf(w3, bf2f(q3.z), acc.z); acc.w = fmaf(w3, bf2f(q3.w), acc.w);
  }
  for (; e < e1; ++e) {
    int2 p0 = csr_sw[e];
    float w0 = __int_as_float(p0.y);
    ushort4 q0 = Q4[(size_t)p0.x * 32 + lane];
    acc.x = fmaf(w0, bf2f(q0.x), acc.x); acc.y = fmaf(w0, bf2f(q0.y), acc.y);
    acc.z = fmaf(w0, bf2f(q0.z), acc.z); acc.w = fmaf(w0, bf2f(q0.w), acc.w);
  }
  acc.x = fmaxf(acc.x, 0.f); acc.y = fmaxf(acc.y, 0.f);
  acc.z = fmaxf(acc.z, 0.f); acc.w = fmaxf(acc.w, 0.f);
  ushort4 h, l;
  h.x = f2bf(acc.x); l.x = f2bf(acc.x - bf2f(h.x));
  h.y = f2bf(acc.y); l.y = f2bf(acc.y - bf2f(h.y));
  h.z = f2bf(acc.z); l.z = f2bf(acc.z - bf2f(h.z));
  h.w = f2bf(acc.w); l.w = f2bf(acc.w - bf2f(h.w));
  size_t o = (size_t)node * 32 + lane;
  ((ushort4*)Ph)[o] = h;
  ((ushort4*)Pl)[o] = l;
}

// ---------- pooling + head ----------

__global__ void k_zero_pool(float* __restrict__ sums, float* __restrict__ counts) {
  int t = blockIdx.x * 256 + threadIdx.x;
  if (t < NG * FD) sums[t] = 0.f;
  if (t < NG) counts[t] = 0.f;
}

#define POOL_BLOCKS 1024
#define POOL_CHUNK 98
__global__ void k_pool(const int* __restrict__ batch, const ushort* __restrict__ Ph,
                       const ushort* __restrict__ Pl, float* __restrict__ sums,
                       float* __restrict__ counts) {
  int f = threadIdx.x;  // 0..127
  int i0 = blockIdx.x * POOL_CHUNK;
  if (i0 >= NN) return;
  int i1 = i0 + POOL_CHUNK;
  if (i1 > NN) i1 = NN;
  float acc = 0.f;
  int gcur = batch[i0];
  int cnt = 0;
  for (int i = i0; i < i1; ++i) {
    int g = batch[i];
    if (g != gcur) {
      atomicAdd(&sums[gcur * FD + f], acc);
      if (f == 0) atomicAdd(&counts[gcur], (float)cnt);
      acc = 0.f; cnt = 0; gcur = g;
    }
    size_t o = (size_t)i * FD + f;
    acc += bf2f(Ph[o]) + bf2f(Pl[o]);
    ++cnt;
  }
  atomicAdd(&sums[gcur * FD + f], acc);
  if (f == 0) atomicAdd(&counts[gcur], (float)cnt);
}

__global__ void k_head(const float* __restrict__ sums, const float* __restrict__ counts,
                       const float* __restrict__ Wm, const float* __restrict__ bm,
                       float* __restrict__ out) {
  int t = blockIdx.x * 256 + threadIdx.x;
  if (t >= NG * NC) return;
  int g = t / NC, c = t % NC;
  float inv = 1.0f / fmaxf(counts[g], 1.0f);
  float s = 0.f;
#pragma unroll 4
  for (int f = 0; f < FD; ++f) s = fmaf(sums[g * FD + f] * inv, Wm[f * NC + c], s);
  out[t] = s + bm[c];
}

extern "C" void kernel_launch(void* const* d_in, const int* in_sizes, int n_in,
                              void* d_out, int out_size, void* d_ws, size_t ws_size,
                              hipStream_t stream) {
  const float* x     = (const float*)d_in[0];
  const int*   ei    = (const int*)d_in[1];
  const int*   batch = (const int*)d_in[2];
  const float* W_in  = (const float*)d_in[3];
  const float* b_in  = (const float*)d_in[4];
  const float* W_mid = (const float*)d_in[5];
  const float* b_mid = (const float*)d_in[6];
  const float* W_mlp = (const float*)d_in[7];
  const float* b_mlp = (const float*)d_in[8];
  float* out = (float*)d_out;

  const int* src = ei;        // edge_index[0]
  const int* dst = ei + NE;   // edge_index[1]

  char* ws = (char*)d_ws;
  ushort* Qh        = (ushort*)ws;  ws += (size_t)NN * FD * 2;   // 25.6 MB
  ushort* Ph        = (ushort*)ws;  ws += (size_t)NN * FD * 2;   // 25.6 MB
  ushort* Pl        = (ushort*)ws;  ws += (size_t)NN * FD * 2;   // 25.6 MB
  float*  dinv      = (float*)ws;   ws += (size_t)NN * 4;
  int*    rowptr    = (int*)ws;     ws += (size_t)(NN + 1) * 4;
  int*    cursor    = (int*)ws;     ws += (size_t)NN * 4;
  int2*   csr_sw    = (int2*)ws;    ws += (size_t)NT * 8;        // 13.6 MB
  int*    blockSums = (int*)ws;     ws += 256 * 4;
  int*    blockOffs = (int*)ws;     ws += 256 * 4;
  ushort* WhA       = (ushort*)ws;  ws += (size_t)FD * FD * 2;
  ushort* WlA       = (ushort*)ws;  ws += (size_t)FD * FD * 2;
  ushort* WhB       = (ushort*)ws;  ws += (size_t)FD * FD * 2;
  ushort* WlB       = (ushort*)ws;  ws += (size_t)FD * FD * 2;
  float*  sums      = (float*)ws;   ws += (size_t)NG * FD * 4;
  float*  counts    = (float*)ws;   ws += (size_t)NG * 4;

  // CSR build (incl. self-loops; reused by all 4 layers)
  k_one_int<<<(NN + 255) / 256, 256, 0, stream>>>(cursor, NN);
  k_count<<<(NE + 255) / 256, 256, 0, stream>>>(dst, cursor);
  k_scanA<<<NB_SCAN, 256, 0, stream>>>(cursor, blockSums);
  k_scanB<<<1, 256, 0, stream>>>(blockSums, blockOffs, rowptr);
  k_scanC<<<NB_SCAN, 256, 0, stream>>>(cursor, blockOffs, rowptr, dinv);
  k_fill<<<(NT + 255) / 256, 256, 0, stream>>>(src, dst, rowptr, cursor, dinv, csr_sw);

  // weight packing + input split
  k_packW<<<(FD * FD + 255) / 256, 256, 0, stream>>>(W_in, WhA, WlA);
  k_packW<<<(FD * FD + 255) / 256, 256, 0, stream>>>(W_mid, WhB, WlB);
  k_split<<<(NN * FD / 4 + 255) / 256, 256, 0, stream>>>(x, Ph, Pl);

  const int gM = (NN + 63) / 64;   // 1563 blocks
  const int gG = (NN + 7) / 8;     // 12500 blocks
  for (int L = 0; L < 4; ++L) {
    const ushort* Wh = (L == 0) ? WhA : WhB;
    const ushort* Wl = (L == 0) ? WlA : WlB;
    const float*  b  = (L == 0) ? b_in : b_mid;
    k_gemm_mfma<<<gM, 256, 0, stream>>>(Ph, Pl, Wh, Wl, Qh);
    k_gather<<<gG, 256, 0, stream>>>(rowptr, csr_sw, Qh, b, Ph, Pl);
  }

  k_zero_pool<<<32, 256, 0, stream>>>(sums, counts);
  k_pool<<<POOL_BLOCKS, 128, 0, stream>>>(batch, Ph, Pl, sums, counts);
  k_head<<<(NG * NC + 255) / 256, 256, 0, stream>>>(sums, counts, W_mlp, b_mlp, out);
}